// Round 3
// baseline (97.905 us; speedup 1.0000x reference)
//
#include <hip/hip_runtime.h>
#include <float.h>

#define BATCH 32
#define NP 512
#define NG 512
#define TSTEP 10
#define NI (NG * TSTEP)        // 5120 interpolated candidates per batch
#define NCHUNK 16
#define CPTS (NI / NCHUNK)     // 320 candidates per chunk
#define NPAIR_CH (CPTS / 2)    // 160 float4 pairs per chunk
#define NPAIR_B (NI / 2)       // 2560 pairs per batch
#define NGROUP 64              // pred groups of 256
#define NPRED (BATCH * NP)     // 16384

typedef float f2 __attribute__((ext_vector_type(2)));

__device__ __forceinline__ float wave_reduce(float v) {
#pragma unroll
    for (int o = 32; o > 0; o >>= 1) v += __shfl_down(v, o);
    return v;
}

// =================== L1: interp table (pair layout) + g2p ===================
// blocks 0..31: interp for batch b -> interpP[b*2560 + q] = (x_{2q}, x_{2q+1}, y_{2q}, y_{2q+1})
// blocks 32..95: gt -> nearest pred (one-pass argmin, uniform global candidate loads)
__global__ __launch_bounds__(256) void k_pre(
    const float* __restrict__ gt, const float* __restrict__ pred0,
    const float* __restrict__ pred1, const float* __restrict__ mask,
    float4* __restrict__ interpP, float* __restrict__ gsum, float* __restrict__ msum,
    unsigned int* __restrict__ counters) {
    const int bid = blockIdx.x, tid = threadIdx.x;
    if (bid == 0 && tid <= NGROUP) counters[tid] = 0u;   // re-arm (L1 completes before L2)

    if (bid < BATCH) {
        const float* gtb = gt + bid * NG * 2;
#pragma unroll
        for (int i = 0; i < NPAIR_B / 256; ++i) {        // 10 pairs/thread, coalesced
            int q = i * 256 + tid;
            int k0 = 2 * q, k1 = 2 * q + 1;
            int j0 = k0 / TSTEP, t0 = k0 - j0 * TSTEP;
            int j1 = k1 / TSTEP, t1 = k1 - j1 * TSTEP;
            int jm0 = (j0 + NG - 1) & (NG - 1), jm1 = (j1 + NG - 1) & (NG - 1);
            float tf0 = (float)t0 / 10.0f, uf0 = 1.0f - tf0;
            float tf1 = (float)t1 / 10.0f, uf1 = 1.0f - tf1;
            // identical expression to rounds 1-2 (absmax 0) — do not change contraction shape
            float x0 = gtb[2 * j0] * tf0 + gtb[2 * jm0] * uf0;
            float y0 = gtb[2 * j0 + 1] * tf0 + gtb[2 * jm0 + 1] * uf0;
            float x1 = gtb[2 * j1] * tf1 + gtb[2 * jm1] * uf1;
            float y1 = gtb[2 * j1 + 1] * tf1 + gtb[2 * jm1 + 1] * uf1;
            interpP[bid * NPAIR_B + q] = make_float4(x0, x1, y0, y1);
        }
    } else {
        __shared__ float swl[4], swm[4];
        const int gb = bid - BATCH;          // 0..63
        const int b = gb >> 1, gh = gb & 1;
        const int g = gh * 256 + tid;
        const float gx = gt[(b * NG + g) * 2], gy = gt[(b * NG + g) * 2 + 1];
        const float4* pp = (const float4*)(pred0 + b * NP * 2);  // uniform: (x0,y0,x1,y1)
        float b0 = FLT_MAX, b1 = FLT_MAX;
        int i0 = 0, i1 = 0;
#pragma unroll 4
        for (int i = 0; i < NP / 2; ++i) {
            float4 c = pp[i];
            float dx, dy, d;
            dx = gx - c.x; dy = gy - c.y; d = fmaf(dy, dy, dx * dx);
            if (d < b0) { b0 = d; i0 = 2 * i; }
            dx = gx - c.z; dy = gy - c.w; d = fmaf(dy, dy, dx * dx);
            if (d < b1) { b1 = d; i1 = 2 * i + 1; }
        }
        // exact first-min combine: dist>=0 -> bit pattern monotone; idx in low bits
        unsigned long long p0 = ((unsigned long long)__float_as_uint(b0) << 32) | (unsigned)i0;
        unsigned long long p1 = ((unsigned long long)__float_as_uint(b1) << 32) | (unsigned)i1;
        const int bi = (int)((p0 < p1 ? p0 : p1) & 0xFFFFFFFFull);
        const float m = mask[b * NG + g];
        float l = m * (fabsf(pred1[(b * NP + bi) * 2] - gx) +
                       fabsf(pred1[(b * NP + bi) * 2 + 1] - gy));
        float mm = 2.0f * m;
        l = wave_reduce(l);
        mm = wave_reduce(mm);
        const int lane = tid & 63, w = tid >> 6;
        if (lane == 0) { swl[w] = l; swm[w] = mm; }
        __syncthreads();
        if (tid == 0) {
            gsum[gb] = swl[0] + swl[1] + swl[2] + swl[3];
            msum[gb] = swm[0] + swm[1] + swm[2] + swm[3];
        }
    }
}

// =================== L2: min-only scan + last-block combine/rescan/final ===================
// 1024 blocks = 64 pred-groups x 16 chunks. Thread = one pred point.
__global__ __launch_bounds__(256) void k_scan(
    const float* __restrict__ pred0, const float* __restrict__ pred1,
    const float4* __restrict__ interpP, float* __restrict__ chunkmin,
    const float* __restrict__ gsum, const float* __restrict__ msum,
    float* __restrict__ psum, unsigned int* __restrict__ counters,
    float* __restrict__ out) {
    __shared__ float sw[4];
    __shared__ int lastFlag, finFlag;
    const int bid = blockIdx.x, tid = threadIdx.x;
    const int grp = bid >> 4, ch = bid & (NCHUNK - 1);
    const int b = grp >> 1;
    const int pr = grp * 256 + tid;            // global pred index (b*512 + ph*256 + tid)
    const float px = pred0[pr * 2], py = pred0[pr * 2 + 1];
    const f2 pxx = {px, px}, pyy = {py, py};

    // ---- pass 1: chunk min (no idx) — uniform candidate loads, packed-f32 math ----
    const float4* cp = interpP + b * NPAIR_B + ch * NPAIR_CH;
    float m0 = FLT_MAX, m1 = FLT_MAX;
#pragma unroll 4
    for (int q = 0; q < NPAIR_CH; q += 2) {
        float4 c0 = cp[q], c1 = cp[q + 1];     // block-uniform -> s_load
        f2 xx0 = {c0.x, c0.y}, yy0 = {c0.z, c0.w};
        f2 dx0 = xx0 - pxx, dy0 = yy0 - pyy;
        f2 d0 = __builtin_elementwise_fma(dy0, dy0, dx0 * dx0);
        m0 = fminf(fminf(d0.x, d0.y), m0);     // -> v_min3_f32
        f2 xx1 = {c1.x, c1.y}, yy1 = {c1.z, c1.w};
        f2 dx1 = xx1 - pxx, dy1 = yy1 - pyy;
        f2 d1 = __builtin_elementwise_fma(dy1, dy1, dx1 * dx1);
        m1 = fminf(fminf(d1.x, d1.y), m1);
    }
    const float cm = fminf(m0, m1);
    __hip_atomic_store(&chunkmin[ch * NPRED + pr], cm, __ATOMIC_RELAXED, __HIP_MEMORY_SCOPE_AGENT);

    __syncthreads();   // all stores of this block retired (vmcnt drain before barrier)
    if (tid == 0) {
        unsigned tk = __hip_atomic_fetch_add(&counters[grp], 1u, __ATOMIC_ACQ_REL, __HIP_MEMORY_SCOPE_AGENT);
        lastFlag = (tk == NCHUNK - 1);
    }
    __syncthreads();
    if (!lastFlag) return;

    // ---- group fin (runs in the last-finishing block of this pred group) ----
    // combine 16 chunk mins; first chunk achieving the min wins (strict <)
    float best = __hip_atomic_load(&chunkmin[pr], __ATOMIC_RELAXED, __HIP_MEMORY_SCOPE_AGENT);
    int wch = 0;
#pragma unroll
    for (int c2 = 1; c2 < NCHUNK; ++c2) {
        float v = __hip_atomic_load(&chunkmin[c2 * NPRED + pr], __ATOMIC_RELAXED, __HIP_MEMORY_SCOPE_AGENT);
        if (v < best) { best = v; wch = c2; }
    }
    // rescan winning chunk: identical IEEE op sequence -> first bitwise match = exact argmin
    const float4* rp = interpP + b * NPAIR_B + wch * NPAIR_CH;   // per-lane divergent
    float nx = 0.f, ny = 0.f;
    bool found = false;
#pragma unroll 4
    for (int q = 0; q < NPAIR_CH; ++q) {
        float4 c = rp[q];
        f2 xx = {c.x, c.y}, yy = {c.z, c.w};
        f2 dx = xx - pxx, dy = yy - pyy;
        f2 d = __builtin_elementwise_fma(dy, dy, dx * dx);
        bool t0 = (d.x == best) && !found;
        nx = t0 ? c.x : nx; ny = t0 ? c.z : ny; found = found || t0;
        bool t1 = (d.y == best) && !found;
        nx = t1 ? c.y : nx; ny = t1 ? c.w : ny; found = found || t1;
    }
    float s = fabsf(pred1[pr * 2] - nx) + fabsf(pred1[pr * 2 + 1] - ny);
    s = wave_reduce(s);
    const int lane = tid & 63, w = tid >> 6;
    if (lane == 0) sw[w] = s;
    __syncthreads();
    if (tid == 0) {
        float S = sw[0] + sw[1] + sw[2] + sw[3];
        __hip_atomic_store(&psum[grp], S, __ATOMIC_RELAXED, __HIP_MEMORY_SCOPE_AGENT);
        unsigned tk2 = __hip_atomic_fetch_add(&counters[NGROUP], 1u, __ATOMIC_ACQ_REL, __HIP_MEMORY_SCOPE_AGENT);
        finFlag = (tk2 == NGROUP - 1);
    }
    __syncthreads();
    if (!finFlag || tid >= 64) return;

    // ---- global final (last group standing; fixed-order reduce -> deterministic) ----
    float a = __hip_atomic_load(&psum[tid], __ATOMIC_RELAXED, __HIP_MEMORY_SCOPE_AGENT);
    float l = gsum[tid];   // written by L1 (kernel-boundary visibility)
    float m = msum[tid];
    a = wave_reduce(a);
    l = wave_reduce(l);
    m = wave_reduce(m);
    if (tid == 0)
        out[0] = (l / (m + 1.0f) + a / (float)(NPRED * 2)) * 0.5f;
}

extern "C" void kernel_launch(void* const* d_in, const int* in_sizes, int n_in,
                              void* d_out, int out_size, void* d_ws, size_t ws_size,
                              hipStream_t stream) {
    const float* pred0 = (const float*)d_in[0];   // ini_pred_poly [B,NP,2]
    const float* pred1 = (const float*)d_in[1];   // pred_polys_   [B,NP,2]
    const float* gt    = (const float*)d_in[2];   // gt_polys      [B,NG,2]
    const float* mask  = (const float*)d_in[3];   // keyPointsMask [B,NG]
    float* out = (float*)d_out;

    char* ws = (char*)d_ws;
    float4* interpP = (float4*)ws;                                   // 32*2560*16 B = 1.3125 MB
    float* chunkmin = (float*)(ws + (size_t)BATCH * NPAIR_B * 16);   // 16*16384*4 = 1 MB
    float* psum = (float*)(ws + (size_t)BATCH * NPAIR_B * 16 + (size_t)NCHUNK * NPRED * 4);
    float* gsum = psum + NGROUP;
    float* msum = gsum + NGROUP;
    unsigned int* counters = (unsigned int*)(msum + NGROUP);         // NGROUP+1

    hipLaunchKernelGGL(k_pre, dim3(BATCH + NGROUP), dim3(256), 0, stream,
                       gt, pred0, pred1, mask, interpP, gsum, msum, counters);
    hipLaunchKernelGGL(k_scan, dim3(NGROUP * NCHUNK), dim3(256), 0, stream,
                       pred0, pred1, interpP, chunkmin, gsum, msum, psum, counters, out);
}

// Round 4
// 59.875 us; speedup vs baseline: 1.6352x; 1.6352x over previous
//
#include <hip/hip_runtime.h>
#include <float.h>

#define BATCH 32
#define NP 512
#define NG 512
#define TSTEP 10
#define NI (NG * TSTEP)        // 5120 interpolated candidates per batch
#define NPAIR_B (NI / 2)       // 2560 float4 pairs per batch (x0,x1,y0,y1)
#define NCHUNK 8               // candidate chunks per pred-group
#define TILES_CH 5             // tiles per chunk; tile = 64 pairs = 128 cands
#define NTILE (NCHUNK * TILES_CH)   // 40 tiles per batch
#define NGROUP 64              // pred groups of 256 (grp = b*2 + half)
#define NPRED (BATCH * NP)     // 16384

typedef float f2 __attribute__((ext_vector_type(2)));

__device__ __forceinline__ float wave_reduce(float v) {
#pragma unroll
    for (int o = 32; o > 0; o >>= 1) v += __shfl_down(v, o);
    return v;
}

__device__ __forceinline__ float rlane(float v, int l) {
    return __int_as_float(__builtin_amdgcn_readlane(__float_as_int(v), l));
}

// =================== K1: interp table (pair layout) + g2p ===================
// blocks 0..31: interp batch b -> interpP[b*2560+q] = (x_{2q},x_{2q+1},y_{2q},y_{2q+1})
// blocks 32..95: gt -> nearest pred (LDS-staged, round-2-proven body)
__global__ __launch_bounds__(256) void k_pre(
    const float* __restrict__ gt, const float* __restrict__ pred0,
    const float* __restrict__ pred1, const float* __restrict__ mask,
    float4* __restrict__ interpP, float* __restrict__ gsum, float* __restrict__ msum,
    unsigned int* __restrict__ counters) {
    const int bid = blockIdx.x, tid = threadIdx.x;
    if (bid == 0 && tid <= NGROUP) counters[tid] = 0u;   // re-arm each call

    if (bid < BATCH) {
        const float* gtb = gt + bid * NG * 2;
#pragma unroll
        for (int i = 0; i < NPAIR_B / 256; ++i) {
            int q = i * 256 + tid;
            int k0 = 2 * q, k1 = 2 * q + 1;
            int j0 = k0 / TSTEP, t0 = k0 - j0 * TSTEP;
            int j1 = k1 / TSTEP, t1 = k1 - j1 * TSTEP;
            int jm0 = (j0 + NG - 1) & (NG - 1), jm1 = (j1 + NG - 1) & (NG - 1);
            float tf0 = (float)t0 / 10.0f, uf0 = 1.0f - tf0;
            float tf1 = (float)t1 / 10.0f, uf1 = 1.0f - tf1;
            // identical contraction shape to rounds 1-3 (absmax 0) — do not change
            float x0 = gtb[2 * j0] * tf0 + gtb[2 * jm0] * uf0;
            float y0 = gtb[2 * j0 + 1] * tf0 + gtb[2 * jm0 + 1] * uf0;
            float x1 = gtb[2 * j1] * tf1 + gtb[2 * jm1] * uf1;
            float y1 = gtb[2 * j1 + 1] * tf1 + gtb[2 * jm1 + 1] * uf1;
            interpP[bid * NPAIR_B + q] = make_float4(x0, x1, y0, y1);
        }
    } else {
        __shared__ float2 sP[NP];
        __shared__ float swl[4], swm[4];
        const int gb = bid - BATCH;          // 0..63
        const int b = gb >> 1, gh = gb & 1;
        for (int k = tid; k < NP; k += 256)
            sP[k] = make_float2(pred0[(b * NP + k) * 2], pred0[(b * NP + k) * 2 + 1]);
        __syncthreads();

        const int g = gh * 256 + tid;
        const float gx = gt[(b * NG + g) * 2], gy = gt[(b * NG + g) * 2 + 1];
        float b0 = FLT_MAX, b1 = FLT_MAX;
        int i0 = 0, i1 = 0;
        const float4* s4 = (const float4*)sP;
#pragma unroll 4
        for (int i = 0; i < NP / 2; ++i) {
            float4 c = s4[i];
            float dx, dy, d;
            dx = gx - c.x; dy = gy - c.y; d = dx * dx + dy * dy;
            if (d < b0) { b0 = d; i0 = 2 * i; }
            dx = gx - c.z; dy = gy - c.w; d = dx * dx + dy * dy;
            if (d < b1) { b1 = d; i1 = 2 * i + 1; }
        }
        unsigned long long p0 = ((unsigned long long)__float_as_uint(b0) << 32) | (unsigned)i0;
        unsigned long long p1 = ((unsigned long long)__float_as_uint(b1) << 32) | (unsigned)i1;
        const int bi = (int)((p0 < p1 ? p0 : p1) & 0xFFFFFFFFull);
        const float m = mask[b * NG + g];
        float l = m * (fabsf(pred1[(b * NP + bi) * 2] - gx) +
                       fabsf(pred1[(b * NP + bi) * 2 + 1] - gy));
        float mm = 2.0f * m;
        l = wave_reduce(l);
        mm = wave_reduce(mm);
        const int lane = tid & 63, w = tid >> 6;
        if (lane == 0) { swl[w] = l; swm[w] = mm; }
        __syncthreads();
        if (tid == 0) {
            gsum[gb] = swl[0] + swl[1] + swl[2] + swl[3];
            msum[gb] = swm[0] + swm[1] + swm[2] + swm[3];
        }
    }
}

// =================== K2: readlane-broadcast min scan ===================
// 512 blocks = 64 pred-groups x 8 chunks. Thread = one pred point.
// Candidate delivery: 1 coalesced float4/lane per 128-cand tile, then 64
// readlane-broadcast rounds — zero memory-pipe traffic in the hot loop.
__global__ __launch_bounds__(256) void k_scan(
    const float* __restrict__ pred0, const float* __restrict__ pred1,
    const float4* __restrict__ interpP, unsigned long long* __restrict__ packs,
    const float* __restrict__ gsum, const float* __restrict__ msum,
    float* __restrict__ psum, unsigned int* __restrict__ counters,
    float* __restrict__ out) {
    __shared__ float sw[4];
    __shared__ int lastFlag, finFlag;
    const int bid = blockIdx.x, tid = threadIdx.x;
    const int grp = bid >> 3, ch = bid & (NCHUNK - 1);
    const int b = grp >> 1;
    const int pr = grp * 256 + tid;
    const float px = pred0[pr * 2], py = pred0[pr * 2 + 1];
    const f2 pxx = {px, px}, pyy = {py, py};
    const float4* cp = interpP + b * NPAIR_B;

    float best = FLT_MAX;
    int btile = ch * TILES_CH;
#pragma unroll
    for (int t = 0; t < TILES_CH; ++t) {
        const int tg = ch * TILES_CH + t;               // global tile 0..39
        const float4 vp = cp[tg * 64 + (tid & 63)];     // 128 cands across the wave
        float accE = FLT_MAX, accO = FLT_MAX;
#pragma unroll
        for (int r = 0; r < 64; r += 2) {
            {   // round r -> accE
                f2 cxx = {rlane(vp.x, r), rlane(vp.y, r)};
                f2 cyy = {rlane(vp.z, r), rlane(vp.w, r)};
                f2 dxx = cxx - pxx, dyy = cyy - pyy;
                f2 d = __builtin_elementwise_fma(dyy, dyy, dxx * dxx);
                accE = fminf(fminf(d.x, d.y), accE);
            }
            {   // round r+1 -> accO
                f2 cxx = {rlane(vp.x, r + 1), rlane(vp.y, r + 1)};
                f2 cyy = {rlane(vp.z, r + 1), rlane(vp.w, r + 1)};
                f2 dxx = cxx - pxx, dyy = cyy - pyy;
                f2 d = __builtin_elementwise_fma(dyy, dyy, dxx * dxx);
                accO = fminf(fminf(d.x, d.y), accO);
            }
        }
        float tm = fminf(accE, accO);
        if (tm < best) { best = tm; btile = tg; }   // strict < -> first tile wins
    }
    // pack: dist bits high, global tile low -> u64 min == exact first-min tile
    packs[ch * NPRED + pr] =
        ((unsigned long long)__float_as_uint(best) << 32) | (unsigned)btile;

    __syncthreads();   // compiler drains vmcnt before barrier -> stores retired
    if (tid == 0) {
        unsigned tk = __hip_atomic_fetch_add(&counters[grp], 1u, __ATOMIC_ACQ_REL,
                                             __HIP_MEMORY_SCOPE_AGENT);
        lastFlag = (tk == NCHUNK - 1);
    }
    __syncthreads();
    if (!lastFlag) return;

    // ---- last block of the group: combine chunks, rescan winning tile ----
    unsigned long long bp = __hip_atomic_load(&packs[pr], __ATOMIC_RELAXED,
                                              __HIP_MEMORY_SCOPE_AGENT);
#pragma unroll
    for (int c = 1; c < NCHUNK; ++c) {
        unsigned long long v = __hip_atomic_load(&packs[c * NPRED + pr], __ATOMIC_RELAXED,
                                                 __HIP_MEMORY_SCOPE_AGENT);
        if (v < bp) bp = v;
    }
    const float bestd = __uint_as_float((unsigned)(bp >> 32));
    const int wt = (int)(bp & 0xFFFFFFFFull);
    const float4* rp = cp + wt * 64;     // per-lane divergent tile base
    float nx = 0.f, ny = 0.f;
    bool found = false;
#pragma unroll 4
    for (int q = 0; q < 64; ++q) {
        float4 c = rp[q];
        f2 cxx = {c.x, c.y}, cyy = {c.z, c.w};
        f2 dxx = cxx - pxx, dyy = cyy - pyy;
        f2 d = __builtin_elementwise_fma(dyy, dyy, dxx * dxx);   // identical IEEE seq
        bool t0 = (d.x == bestd) && !found;
        nx = t0 ? c.x : nx; ny = t0 ? c.z : ny; found = found || t0;
        bool t1 = (d.y == bestd) && !found;
        nx = t1 ? c.y : nx; ny = t1 ? c.w : ny; found = found || t1;
    }
    float s = fabsf(pred1[pr * 2] - nx) + fabsf(pred1[pr * 2 + 1] - ny);
    s = wave_reduce(s);
    const int lane = tid & 63, w = tid >> 6;
    if (lane == 0) sw[w] = s;
    __syncthreads();
    if (tid == 0) {
        float S = sw[0] + sw[1] + sw[2] + sw[3];
        __hip_atomic_store(&psum[grp], S, __ATOMIC_RELAXED, __HIP_MEMORY_SCOPE_AGENT);
        unsigned tk2 = __hip_atomic_fetch_add(&counters[NGROUP], 1u, __ATOMIC_ACQ_REL,
                                              __HIP_MEMORY_SCOPE_AGENT);
        finFlag = (tk2 == NGROUP - 1);
    }
    __syncthreads();
    if (!finFlag || tid >= 64) return;

    // ---- global final (last group standing; fixed-order -> deterministic) ----
    float a = __hip_atomic_load(&psum[tid], __ATOMIC_RELAXED, __HIP_MEMORY_SCOPE_AGENT);
    float l = gsum[tid];
    float m = msum[tid];
    a = wave_reduce(a);
    l = wave_reduce(l);
    m = wave_reduce(m);
    if (tid == 0)
        out[0] = (l / (m + 1.0f) + a / (float)(NPRED * 2)) * 0.5f;
}

extern "C" void kernel_launch(void* const* d_in, const int* in_sizes, int n_in,
                              void* d_out, int out_size, void* d_ws, size_t ws_size,
                              hipStream_t stream) {
    const float* pred0 = (const float*)d_in[0];   // ini_pred_poly [B,NP,2]
    const float* pred1 = (const float*)d_in[1];   // pred_polys_   [B,NP,2]
    const float* gt    = (const float*)d_in[2];   // gt_polys      [B,NG,2]
    const float* mask  = (const float*)d_in[3];   // keyPointsMask [B,NG]
    float* out = (float*)d_out;

    char* ws = (char*)d_ws;
    float4* interpP = (float4*)ws;                                       // 1.3125 MB
    unsigned long long* packs =
        (unsigned long long*)(ws + (size_t)BATCH * NPAIR_B * 16);        // 8*16384*8 = 1 MB
    float* psum = (float*)(ws + (size_t)BATCH * NPAIR_B * 16 +
                           (size_t)NCHUNK * NPRED * 8);
    float* gsum = psum + NGROUP;
    float* msum = gsum + NGROUP;
    unsigned int* counters = (unsigned int*)(msum + NGROUP);             // NGROUP+1

    hipLaunchKernelGGL(k_pre, dim3(BATCH + NGROUP), dim3(256), 0, stream,
                       gt, pred0, pred1, mask, interpP, gsum, msum, counters);
    hipLaunchKernelGGL(k_scan, dim3(NGROUP * NCHUNK), dim3(256), 0, stream,
                       pred0, pred1, interpP, packs, gsum, msum, psum, counters, out);
}

// Round 5
// 50.935 us; speedup vs baseline: 1.9221x; 1.1755x over previous
//
#include <hip/hip_runtime.h>
#include <float.h>

#define BATCH 32
#define NP 512
#define NG 512
#define TSTEP 10
#define NI (NG * TSTEP)                 // 5120 interpolated candidates per batch
#define NCHUNK 32                       // candidate chunks per batch
#define CH_CANDS (NI / NCHUNK)          // 160 cands per chunk
#define CH_PAIRS (CH_CANDS / 2)         // 80 float4 pairs per chunk
#define TILE_CANDS 16
#define TILE_PAIRS 8
#define TILES_CH (CH_CANDS / TILE_CANDS)  // 10 tiles/chunk; 320 global tiles/batch
#define NB_SCAN (BATCH * NCHUNK)        // 1024
#define NB_G2P 128                      // 4 blocks per batch, 128 gt pts each
#define THR 128
#define NPRED (BATCH * NP)              // 16384

typedef float f2 __attribute__((ext_vector_type(2)));

__device__ __forceinline__ float wave_reduce(float v) {
#pragma unroll
    for (int o = 32; o > 0; o >>= 1) v += __shfl_down(v, o);
    return v;
}

// ---------------- K1: init ----------------
__global__ __launch_bounds__(256) void k_init(unsigned long long* __restrict__ minpack,
                                              unsigned int* __restrict__ counters) {
    const int t = blockIdx.x * 256 + threadIdx.x;
    if (t < NPRED) minpack[t] = 0xFFFFFFFFFFFFFFFFull;
    if (t <= BATCH) counters[t] = 0u;   // [0..31] batch arrivals, [32] global
}

// global arrival + (for the 160th arriver) final scalar. Block-uniform sync use.
__device__ __forceinline__ void arrive_final(
    unsigned int* counters, const float* psum, const float* gsum, const float* msum,
    float* out, int tid, int* finFlag, float* sred) {
    if (tid == 0) {
        unsigned tk = __hip_atomic_fetch_add(&counters[BATCH], 1u, __ATOMIC_ACQ_REL,
                                             __HIP_MEMORY_SCOPE_AGENT);
        *finFlag = (tk == (unsigned)(BATCH + NB_G2P - 1));
    }
    __syncthreads();
    if (!*finFlag) return;
    float a = tid < BATCH ? __hip_atomic_load(&psum[tid], __ATOMIC_RELAXED, __HIP_MEMORY_SCOPE_AGENT) : 0.0f;
    float l = __hip_atomic_load(&gsum[tid], __ATOMIC_RELAXED, __HIP_MEMORY_SCOPE_AGENT);
    float m = __hip_atomic_load(&msum[tid], __ATOMIC_RELAXED, __HIP_MEMORY_SCOPE_AGENT);
    a = wave_reduce(a);
    l = wave_reduce(l);
    m = wave_reduce(m);
    if ((tid & 63) == 0) { int w = tid >> 6; sred[w * 3] = a; sred[w * 3 + 1] = l; sred[w * 3 + 2] = m; }
    __syncthreads();
    if (tid == 0) {
        float A = sred[0] + sred[3], L = sred[1] + sred[4], M = sred[2] + sred[5];
        out[0] = (L / (M + 1.0f) + A / (float)(NPRED * 2)) * 0.5f;
    }
}

// ---------------- K2: everything ----------------
// blocks [0,1024): (batch,chunk) scan — self-staged interp chunk in LDS,
//   R=4 preds/thread, min-only per 16-cand tile, atomicMin packed u64.
//   Last chunk-block per batch: rescan winning tiles + L1 reduce -> psum[b].
// blocks [1024,1152): gt -> nearest pred (round-2-proven body) -> gsum/msum.
// 160th global arriver computes the final scalar.
__global__ __launch_bounds__(THR) void k_main(
    const float* __restrict__ gt, const float* __restrict__ pred0,
    const float* __restrict__ pred1, const float* __restrict__ mask,
    unsigned long long* __restrict__ minpack,
    float* __restrict__ psum, float* __restrict__ gsum, float* __restrict__ msum,
    unsigned int* __restrict__ counters, float* __restrict__ out) {
    __shared__ float2 sTFU[TSTEP];      // (tf, 1-tf) — single source of truth for interp weights
    __shared__ float4 sC4[CH_PAIRS];    // chunk candidates, pair layout (x0,x1,y0,y1)
    __shared__ float2 sP[NP];           // g2p pred stage
    __shared__ float swl[2], swm[2], sred[6];
    __shared__ int lastFlag, finFlag;
    const int bid = blockIdx.x, tid = threadIdx.x;

    if (bid < NB_SCAN) {
        const int b = bid >> 5, ch = bid & (NCHUNK - 1);
        const float* gtb = gt + b * NG * 2;
        if (tid < TSTEP) {
            float tf = (float)tid / 10.0f;           // same expr as rounds 1-4
            sTFU[tid] = make_float2(tf, 1.0f - tf);
        }
        __syncthreads();
        if (tid < CH_PAIRS) {   // stage 2 cands/thread via explicit mul+fma (bitwise-stable)
            int k0 = ch * CH_CANDS + 2 * tid, k1 = k0 + 1;
            int j0 = k0 / TSTEP, t0 = k0 - j0 * TSTEP;
            int j1 = k1 / TSTEP, t1 = k1 - j1 * TSTEP;
            int jm0 = (j0 + NG - 1) & (NG - 1), jm1 = (j1 + NG - 1) & (NG - 1);
            float2 w0 = sTFU[t0], w1 = sTFU[t1];
            float x0 = fmaf(gtb[2 * j0], w0.x, gtb[2 * jm0] * w0.y);
            float y0 = fmaf(gtb[2 * j0 + 1], w0.x, gtb[2 * jm0 + 1] * w0.y);
            float x1 = fmaf(gtb[2 * j1], w1.x, gtb[2 * jm1] * w1.y);
            float y1 = fmaf(gtb[2 * j1 + 1], w1.x, gtb[2 * jm1 + 1] * w1.y);
            sC4[tid] = make_float4(x0, x1, y0, y1);
        }
        f2 PX[4], PY[4];
#pragma unroll
        for (int r = 0; r < 4; ++r) {   // constant-indexed after unroll -> registers
            const float2 p = *(const float2*)(pred0 + (b * NP + r * THR + tid) * 2);
            PX[r] = (f2){p.x, p.x};
            PY[r] = (f2){p.y, p.y};
        }
        __syncthreads();

        float best[4];
        int btile[4];
#pragma unroll
        for (int r = 0; r < 4; ++r) { best[r] = FLT_MAX; btile[r] = 0; }
#pragma unroll 1
        for (int t = 0; t < TILES_CH; ++t) {   // rolled: keep body in i-cache
            float acc[4];
#pragma unroll
            for (int r = 0; r < 4; ++r) acc[r] = FLT_MAX;
#pragma unroll
            for (int qq = 0; qq < TILE_PAIRS; ++qq) {
                const float4 c = sC4[t * TILE_PAIRS + qq];   // uniform broadcast read
                const f2 cx = {c.x, c.y}, cy = {c.z, c.w};
#pragma unroll
                for (int r = 0; r < 4; ++r) {
                    f2 dx = cx - PX[r], dy = cy - PY[r];
                    f2 d = __builtin_elementwise_fma(dy, dy, dx * dx);
                    acc[r] = fminf(fminf(d.x, d.y), acc[r]);   // v_min3
                }
            }
            const int tg = ch * TILES_CH + t;   // global tile id (chunk-ordered)
#pragma unroll
            for (int r = 0; r < 4; ++r)
                if (acc[r] < best[r]) { best[r] = acc[r]; btile[r] = tg; }  // strict <
        }
        // dist>=0 -> bits monotone; tile in low bits -> u64 min = exact first-min tile
#pragma unroll
        for (int r = 0; r < 4; ++r)
            atomicMin(&minpack[b * NP + r * THR + tid],
                      ((unsigned long long)__float_as_uint(best[r]) << 32) | (unsigned)btile[r]);

        __syncthreads();
        if (tid == 0) {
            unsigned tk = __hip_atomic_fetch_add(&counters[b], 1u, __ATOMIC_ACQ_REL,
                                                 __HIP_MEMORY_SCOPE_AGENT);
            lastFlag = (tk == NCHUNK - 1);
        }
        __syncthreads();
        if (!lastFlag) return;

        // ---- batch combine: rescan winning tile per pred (bitwise-identical interp+dist) ----
        float s = 0.0f;
#pragma unroll
        for (int r = 0; r < 4; ++r) {
            const int pr = b * NP + r * THR + tid;
            const unsigned long long bp =
                __hip_atomic_load(&minpack[pr], __ATOMIC_RELAXED, __HIP_MEMORY_SCOPE_AGENT);
            const float bestd = __uint_as_float((unsigned)(bp >> 32));
            const int wt = (int)(bp & 0xFFFFFFFFull);
            float nx = 0.f, ny = 0.f;
            bool found = false;
#pragma unroll 1
            for (int q = 0; q < TILE_PAIRS; ++q) {
                int k0 = wt * TILE_CANDS + 2 * q, k1 = k0 + 1;
                int j0 = k0 / TSTEP, t0 = k0 - j0 * TSTEP;
                int j1 = k1 / TSTEP, t1 = k1 - j1 * TSTEP;
                int jm0 = (j0 + NG - 1) & (NG - 1), jm1 = (j1 + NG - 1) & (NG - 1);
                float2 w0 = sTFU[t0], w1 = sTFU[t1];
                float x0 = fmaf(gtb[2 * j0], w0.x, gtb[2 * jm0] * w0.y);
                float y0 = fmaf(gtb[2 * j0 + 1], w0.x, gtb[2 * jm0 + 1] * w0.y);
                float x1 = fmaf(gtb[2 * j1], w1.x, gtb[2 * jm1] * w1.y);
                float y1 = fmaf(gtb[2 * j1 + 1], w1.x, gtb[2 * jm1 + 1] * w1.y);
                f2 cx = {x0, x1}, cy = {y0, y1};
                f2 dx = cx - PX[r], dy = cy - PY[r];
                f2 d = __builtin_elementwise_fma(dy, dy, dx * dx);
                bool m0 = (d.x == bestd) && !found;
                nx = m0 ? x0 : nx; ny = m0 ? y0 : ny; found = found || m0;
                bool m1 = (d.y == bestd) && !found;
                nx = m1 ? x1 : nx; ny = m1 ? y1 : ny; found = found || m1;
            }
            s += fabsf(pred1[pr * 2] - nx) + fabsf(pred1[pr * 2 + 1] - ny);
        }
        s = wave_reduce(s);
        if ((tid & 63) == 0) swl[tid >> 6] = s;
        __syncthreads();
        if (tid == 0)
            __hip_atomic_store(&psum[b], swl[0] + swl[1], __ATOMIC_RELAXED,
                               __HIP_MEMORY_SCOPE_AGENT);
        arrive_final(counters, psum, gsum, msum, out, tid, &finFlag, sred);
    } else {
        // ---------------- g2p: gt -> nearest pred ----------------
        const int gb = bid - NB_SCAN;         // 0..127
        const int b = gb >> 2, qd = gb & 3;
        for (int k = tid; k < NP; k += THR)
            sP[k] = make_float2(pred0[(b * NP + k) * 2], pred0[(b * NP + k) * 2 + 1]);
        __syncthreads();

        const int g = qd * THR + tid;
        const float gx = gt[(b * NG + g) * 2], gy = gt[(b * NG + g) * 2 + 1];
        float b0 = FLT_MAX, b1 = FLT_MAX;
        int i0 = 0, i1 = 0;
        const float4* s4 = (const float4*)sP;
#pragma unroll 4
        for (int i = 0; i < NP / 2; ++i) {
            float4 c = s4[i];
            float dx, dy, d;
            dx = gx - c.x; dy = gy - c.y; d = dx * dx + dy * dy;
            if (d < b0) { b0 = d; i0 = 2 * i; }
            dx = gx - c.z; dy = gy - c.w; d = dx * dx + dy * dy;
            if (d < b1) { b1 = d; i1 = 2 * i + 1; }
        }
        unsigned long long p0 = ((unsigned long long)__float_as_uint(b0) << 32) | (unsigned)i0;
        unsigned long long p1 = ((unsigned long long)__float_as_uint(b1) << 32) | (unsigned)i1;
        const int bi = (int)((p0 < p1 ? p0 : p1) & 0xFFFFFFFFull);
        const float m = mask[b * NG + g];
        float l = m * (fabsf(pred1[(b * NP + bi) * 2] - gx) +
                       fabsf(pred1[(b * NP + bi) * 2 + 1] - gy));
        float mm = 2.0f * m;
        l = wave_reduce(l);
        mm = wave_reduce(mm);
        if ((tid & 63) == 0) { swl[tid >> 6] = l; swm[tid >> 6] = mm; }
        __syncthreads();
        if (tid == 0) {
            gsum[gb] = swl[0] + swl[1];
            msum[gb] = swm[0] + swm[1];
        }
        arrive_final(counters, psum, gsum, msum, out, tid, &finFlag, sred);
    }
}

extern "C" void kernel_launch(void* const* d_in, const int* in_sizes, int n_in,
                              void* d_out, int out_size, void* d_ws, size_t ws_size,
                              hipStream_t stream) {
    const float* pred0 = (const float*)d_in[0];   // ini_pred_poly [B,NP,2]
    const float* pred1 = (const float*)d_in[1];   // pred_polys_   [B,NP,2]
    const float* gt    = (const float*)d_in[2];   // gt_polys      [B,NG,2]
    const float* mask  = (const float*)d_in[3];   // keyPointsMask [B,NG]
    float* out = (float*)d_out;

    char* ws = (char*)d_ws;
    unsigned long long* minpack = (unsigned long long*)ws;        // 16384*8 = 128 KB
    float* psum = (float*)(ws + (size_t)NPRED * 8);               // 32
    float* gsum = psum + BATCH;                                   // 128
    float* msum = gsum + NB_G2P;                                  // 128
    unsigned int* counters = (unsigned int*)(msum + NB_G2P);      // 33

    hipLaunchKernelGGL(k_init, dim3(64), dim3(256), 0, stream, minpack, counters);
    hipLaunchKernelGGL(k_main, dim3(NB_SCAN + NB_G2P), dim3(THR), 0, stream,
                       gt, pred0, pred1, mask, minpack, psum, gsum, msum, counters, out);
}

// Round 6
// 30.665 us; speedup vs baseline: 3.1927x; 1.6610x over previous
//
#include <hip/hip_runtime.h>
#include <float.h>

#define BATCH 32
#define NP 512
#define NG 512
#define TSTEP 10
#define NI (NG * TSTEP)                   // 5120 candidates per batch
#define NCHUNK 16                         // chunks per batch
#define CH_CANDS (NI / NCHUNK)            // 320 cands per chunk
#define CH_PAIRS (CH_CANDS / 2)           // 160 float4 pairs per chunk
#define TILE_CANDS 16
#define TILE_PAIRS 8
#define TILES_CH (CH_CANDS / TILE_CANDS)  // 20 tiles per chunk; 320 tiles per batch
#define NB_SCAN (BATCH * NCHUNK)          // 512
#define NB_G2P 64                         // 2 blocks per batch, 256 gt pts each
#define NPRED (BATCH * NP)                // 16384

typedef float f2 __attribute__((ext_vector_type(2)));

__device__ __forceinline__ float wave_reduce(float v) {
#pragma unroll
    for (int o = 32; o > 0; o >>= 1) v += __shfl_down(v, o);
    return v;
}

// =================== K_A: scan (chunk minima, plain stores) + g2p ===================
// blocks [0,512): (batch,chunk) — stage interp chunk in LDS, R=2 preds/thread,
//   min-only per 16-cand tile, plain u64 store of (dist|tile) per (chunk,pred).
// blocks [512,576): gt -> nearest pred (round-2-proven body) -> gsum/msum.
// NO atomics anywhere — all combining happens across kernel boundaries.
__global__ __launch_bounds__(256) void k_scan(
    const float* __restrict__ gt, const float* __restrict__ pred0,
    const float* __restrict__ pred1, const float* __restrict__ mask,
    unsigned long long* __restrict__ packs,
    float* __restrict__ gsum, float* __restrict__ msum) {
    __shared__ float2 sTFU[TSTEP];      // (tf, 1-tf) interp weights
    __shared__ float4 sC4[CH_PAIRS];    // chunk candidates, pair layout (x0,x1,y0,y1)
    __shared__ float2 sP[NP];           // g2p pred stage
    __shared__ float swl[4], swm[4];
    const int bid = blockIdx.x, tid = threadIdx.x;

    if (bid < NB_SCAN) {
        const int b = bid >> 4, ch = bid & (NCHUNK - 1);
        const float* gtb = gt + b * NG * 2;
        if (tid < TSTEP) {
            float tf = (float)tid / 10.0f;           // same expr as rounds 1-5
            sTFU[tid] = make_float2(tf, 1.0f - tf);
        }
        __syncthreads();
        if (tid < CH_PAIRS) {   // stage 2 cands/thread — bitwise-identical to round 5
            int k0 = ch * CH_CANDS + 2 * tid, k1 = k0 + 1;
            int j0 = k0 / TSTEP, t0 = k0 - j0 * TSTEP;
            int j1 = k1 / TSTEP, t1 = k1 - j1 * TSTEP;
            int jm0 = (j0 + NG - 1) & (NG - 1), jm1 = (j1 + NG - 1) & (NG - 1);
            float2 w0 = sTFU[t0], w1 = sTFU[t1];
            float x0 = fmaf(gtb[2 * j0], w0.x, gtb[2 * jm0] * w0.y);
            float y0 = fmaf(gtb[2 * j0 + 1], w0.x, gtb[2 * jm0 + 1] * w0.y);
            float x1 = fmaf(gtb[2 * j1], w1.x, gtb[2 * jm1] * w1.y);
            float y1 = fmaf(gtb[2 * j1 + 1], w1.x, gtb[2 * jm1 + 1] * w1.y);
            sC4[tid] = make_float4(x0, x1, y0, y1);
        }
        f2 PX[2], PY[2];
#pragma unroll
        for (int r = 0; r < 2; ++r) {
            const float2 p = *(const float2*)(pred0 + (b * NP + r * 256 + tid) * 2);
            PX[r] = (f2){p.x, p.x};
            PY[r] = (f2){p.y, p.y};
        }
        __syncthreads();

        float best[2] = {FLT_MAX, FLT_MAX};
        int btile[2] = {0, 0};
#pragma unroll 1
        for (int t = 0; t < TILES_CH; ++t) {
            float acc[2] = {FLT_MAX, FLT_MAX};
#pragma unroll
            for (int q = 0; q < TILE_PAIRS; ++q) {
                const float4 c = sC4[t * TILE_PAIRS + q];   // uniform broadcast read
                const f2 cx = {c.x, c.y}, cy = {c.z, c.w};
#pragma unroll
                for (int r = 0; r < 2; ++r) {
                    f2 dx = cx - PX[r], dy = cy - PY[r];
                    f2 d = __builtin_elementwise_fma(dy, dy, dx * dx);
                    acc[r] = fminf(fminf(d.x, d.y), acc[r]);
                }
            }
            const int tg = ch * TILES_CH + t;   // global tile id, ascending with chunk
#pragma unroll
            for (int r = 0; r < 2; ++r)
                if (acc[r] < best[r]) { best[r] = acc[r]; btile[r] = tg; }  // strict <
        }
        // dist>=0 -> bits monotone; tile in low bits -> u64 min = exact first-min tile.
        // PLAIN stores (no RMW at the coherent point) — combined next kernel.
#pragma unroll
        for (int r = 0; r < 2; ++r)
            packs[(size_t)ch * NPRED + b * NP + r * 256 + tid] =
                ((unsigned long long)__float_as_uint(best[r]) << 32) | (unsigned)btile[r];
    } else {
        // ---------------- g2p: gt -> nearest pred (round-2-proven body) ----------------
        const int gb = bid - NB_SCAN;        // 0..63
        const int b = gb >> 1, gh = gb & 1;
        for (int k = tid; k < NP; k += 256)
            sP[k] = make_float2(pred0[(b * NP + k) * 2], pred0[(b * NP + k) * 2 + 1]);
        __syncthreads();

        const int g = gh * 256 + tid;
        const float gx = gt[(b * NG + g) * 2], gy = gt[(b * NG + g) * 2 + 1];
        float b0 = FLT_MAX, b1 = FLT_MAX;
        int i0 = 0, i1 = 0;
        const float4* s4 = (const float4*)sP;
#pragma unroll 4
        for (int i = 0; i < NP / 2; ++i) {
            float4 c = s4[i];
            float dx, dy, d;
            dx = gx - c.x; dy = gy - c.y; d = dx * dx + dy * dy;
            if (d < b0) { b0 = d; i0 = 2 * i; }
            dx = gx - c.z; dy = gy - c.w; d = dx * dx + dy * dy;
            if (d < b1) { b1 = d; i1 = 2 * i + 1; }
        }
        unsigned long long p0 = ((unsigned long long)__float_as_uint(b0) << 32) | (unsigned)i0;
        unsigned long long p1 = ((unsigned long long)__float_as_uint(b1) << 32) | (unsigned)i1;
        const int bi = (int)((p0 < p1 ? p0 : p1) & 0xFFFFFFFFull);
        const float m = mask[b * NG + g];
        float l = m * (fabsf(pred1[(b * NP + bi) * 2] - gx) +
                       fabsf(pred1[(b * NP + bi) * 2 + 1] - gy));
        float mm = 2.0f * m;
        l = wave_reduce(l);
        mm = wave_reduce(mm);
        if ((tid & 63) == 0) { swl[tid >> 6] = l; swm[tid >> 6] = mm; }
        __syncthreads();
        if (tid == 0) {
            gsum[gb] = swl[0] + swl[1] + swl[2] + swl[3];
            msum[gb] = swm[0] + swm[1] + swm[2] + swm[3];
        }
    }
}

// =================== K_B: fold chunk packs + rescan winning tile + L1 reduce ===================
// 64 blocks x 256 threads; thread = one pred point.
__global__ __launch_bounds__(256) void k_comb(
    const float* __restrict__ gt, const float* __restrict__ pred0,
    const float* __restrict__ pred1, const unsigned long long* __restrict__ packs,
    float* __restrict__ psum) {
    __shared__ float2 sTFU[TSTEP];
    __shared__ float sw[4];
    const int tid = threadIdx.x;
    const int pr = blockIdx.x * 256 + tid;
    const int b = pr >> 9;
    const float* gtb = gt + b * NG * 2;
    if (tid < TSTEP) {
        float tf = (float)tid / 10.0f;
        sTFU[tid] = make_float2(tf, 1.0f - tf);
    }
    __syncthreads();

    // u64-min fold over 16 chunk packs = exact global first-min (tile ids ordered)
    unsigned long long bp = packs[pr];
#pragma unroll
    for (int c = 1; c < NCHUNK; ++c) {
        unsigned long long v = packs[(size_t)c * NPRED + pr];
        if (v < bp) bp = v;
    }
    const float bestd = __uint_as_float((unsigned)(bp >> 32));
    const int wt = (int)(bp & 0xFFFFFFFFull);

    const float2 p = *(const float2*)(pred0 + pr * 2);
    const f2 pxx = {p.x, p.x}, pyy = {p.y, p.y};
    float nx = 0.f, ny = 0.f;
    bool found = false;
#pragma unroll
    for (int q = 0; q < TILE_PAIRS; ++q) {   // bitwise-identical recompute (round-5-proven)
        int k0 = wt * TILE_CANDS + 2 * q, k1 = k0 + 1;
        int j0 = k0 / TSTEP, t0 = k0 - j0 * TSTEP;
        int j1 = k1 / TSTEP, t1 = k1 - j1 * TSTEP;
        int jm0 = (j0 + NG - 1) & (NG - 1), jm1 = (j1 + NG - 1) & (NG - 1);
        float2 w0 = sTFU[t0], w1 = sTFU[t1];
        float x0 = fmaf(gtb[2 * j0], w0.x, gtb[2 * jm0] * w0.y);
        float y0 = fmaf(gtb[2 * j0 + 1], w0.x, gtb[2 * jm0 + 1] * w0.y);
        float x1 = fmaf(gtb[2 * j1], w1.x, gtb[2 * jm1] * w1.y);
        float y1 = fmaf(gtb[2 * j1 + 1], w1.x, gtb[2 * jm1 + 1] * w1.y);
        f2 cx = {x0, x1}, cy = {y0, y1};
        f2 dx = cx - pxx, dy = cy - pyy;
        f2 d = __builtin_elementwise_fma(dy, dy, dx * dx);
        bool m0 = (d.x == bestd) && !found;
        nx = m0 ? x0 : nx; ny = m0 ? y0 : ny; found = found || m0;
        bool m1 = (d.y == bestd) && !found;
        nx = m1 ? x1 : nx; ny = m1 ? y1 : ny; found = found || m1;
    }
    float s = fabsf(pred1[pr * 2] - nx) + fabsf(pred1[pr * 2 + 1] - ny);
    s = wave_reduce(s);
    if ((tid & 63) == 0) sw[tid >> 6] = s;
    __syncthreads();
    if (tid == 0) psum[blockIdx.x] = sw[0] + sw[1] + sw[2] + sw[3];
}

// =================== K_C: final scalar ===================
__global__ __launch_bounds__(64) void k_final(
    const float* __restrict__ psum, const float* __restrict__ gsum,
    const float* __restrict__ msum, float* __restrict__ out) {
    const int t = threadIdx.x;
    float a = psum[t];   // 64 block sums (pred2gt L1)
    float l = gsum[t];   // 64 g2p loss partials
    float m = msum[t];   // 64 g2p mask partials
    a = wave_reduce(a);
    l = wave_reduce(l);
    m = wave_reduce(m);
    if (t == 0)
        out[0] = (l / (m + 1.0f) + a / (float)(NPRED * 2)) * 0.5f;
}

extern "C" void kernel_launch(void* const* d_in, const int* in_sizes, int n_in,
                              void* d_out, int out_size, void* d_ws, size_t ws_size,
                              hipStream_t stream) {
    const float* pred0 = (const float*)d_in[0];   // ini_pred_poly [B,NP,2]
    const float* pred1 = (const float*)d_in[1];   // pred_polys_   [B,NP,2]
    const float* gt    = (const float*)d_in[2];   // gt_polys      [B,NG,2]
    const float* mask  = (const float*)d_in[3];   // keyPointsMask [B,NG]
    float* out = (float*)d_out;

    char* ws = (char*)d_ws;
    unsigned long long* packs = (unsigned long long*)ws;          // 16*16384*8 = 2 MB
    float* psum = (float*)(ws + (size_t)NCHUNK * NPRED * 8);      // 64
    float* gsum = psum + 64;                                      // 64
    float* msum = gsum + 64;                                      // 64

    hipLaunchKernelGGL(k_scan, dim3(NB_SCAN + NB_G2P), dim3(256), 0, stream,
                       gt, pred0, pred1, mask, packs, gsum, msum);
    hipLaunchKernelGGL(k_comb, dim3(64), dim3(256), 0, stream,
                       gt, pred0, pred1, packs, psum);
    hipLaunchKernelGGL(k_final, dim3(1), dim3(64), 0, stream,
                       psum, gsum, msum, out);
}